// Round 1
// baseline (4655.615 us; speedup 1.0000x reference)
//
#include <hip/hip_runtime.h>

#define NN    50000   // nodes
#define NHE   50000   // hyperedges
#define NEDGE 320000  // incidence pairs
#define DD    256     // feature dim

// ---------------- degree accumulation ----------------
__global__ __launch_bounds__(256) void k_degrees(const int* __restrict__ src,
                                                 const int* __restrict__ he,
                                                 float* __restrict__ deg_n,
                                                 float* __restrict__ deg_e) {
    int e = blockIdx.x * 256 + threadIdx.x;
    if (e >= NEDGE) return;
    atomicAdd(&deg_n[src[e]], 1.0f);
    atomicAdd(&deg_e[he[e]], 1.0f);
}

// ---------------- tiled fp32 GEMM: C[m,n] = sum_k A[m,k] * W[n,k] ----------------
// A: [M,256] row-major, W: [256,256] row-major, C: [M,256]
// 64x64 tile per block, 256 threads, 4x4 microtile per thread, BK=16.
__global__ __launch_bounds__(256) void k_gemm_nt(const float* __restrict__ A,
                                                 const float* __restrict__ W,
                                                 float* __restrict__ C, int M) {
    __shared__ float As[16][68];  // k-major: As[kk][m], pad to 68 for bank spread
    __shared__ float Ws[16][68];  // k-major: Ws[kk][n]
    const int t    = threadIdx.x;
    const int m0   = blockIdx.x * 64;
    const int n0   = blockIdx.y * 64;
    const int lrow = t >> 2;          // 0..63
    const int lcol = (t & 3) << 2;    // 0,4,8,12
    const int ty   = t >> 4;          // 0..15 -> m-microtile
    const int tx   = t & 15;          // 0..15 -> n-microtile

    float acc[4][4] = {{0.f}};

    const int gm = m0 + lrow;
    const float* Arow = A + (size_t)gm * DD;
    const float* Wrow = W + (size_t)(n0 + lrow) * DD;  // n0+lrow < 256 always

    for (int k0 = 0; k0 < DD; k0 += 16) {
        float4 av = make_float4(0.f, 0.f, 0.f, 0.f);
        if (gm < M) av = *(const float4*)(Arow + k0 + lcol);
        float4 wv = *(const float4*)(Wrow + k0 + lcol);
        __syncthreads();  // protect previous iteration's LDS reads
        As[lcol + 0][lrow] = av.x;
        As[lcol + 1][lrow] = av.y;
        As[lcol + 2][lrow] = av.z;
        As[lcol + 3][lrow] = av.w;
        Ws[lcol + 0][lrow] = wv.x;
        Ws[lcol + 1][lrow] = wv.y;
        Ws[lcol + 2][lrow] = wv.z;
        Ws[lcol + 3][lrow] = wv.w;
        __syncthreads();
#pragma unroll
        for (int kk = 0; kk < 16; ++kk) {
            float4 af = *(const float4*)&As[kk][ty * 4];
            float4 bf = *(const float4*)&Ws[kk][tx * 4];
            const float aarr[4] = {af.x, af.y, af.z, af.w};
            const float barr[4] = {bf.x, bf.y, bf.z, bf.w};
#pragma unroll
            for (int i = 0; i < 4; ++i)
#pragma unroll
                for (int j = 0; j < 4; ++j)
                    acc[i][j] = fmaf(aarr[i], barr[j], acc[i][j]);
        }
    }
#pragma unroll
    for (int i = 0; i < 4; ++i) {
        int gmo = m0 + ty * 4 + i;
        if (gmo < M) {
            float4 v = make_float4(acc[i][0], acc[i][1], acc[i][2], acc[i][3]);
            *(float4*)(C + (size_t)gmo * DD + n0 + tx * 4) = v;
        }
    }
}

// ---------------- edge scatter: dst[sidx[e]] += srcbuf[gidx[e]] * scale ----------------
// 64 lanes per edge, float4 per lane. gdeg != nullptr -> scale = 1/deg[gidx[e]].
__global__ __launch_bounds__(256) void k_scatter(const float* __restrict__ srcbuf,
                                                 float* __restrict__ dst,
                                                 const int* __restrict__ gidx,
                                                 const int* __restrict__ sidx,
                                                 const float* __restrict__ gdeg) {
    int tid  = blockIdx.x * 256 + threadIdx.x;
    int e    = tid >> 6;
    int lane = tid & 63;
    if (e >= NEDGE) return;
    int g = gidx[e];
    int s = sidx[e];
    float sc = 1.0f;
    if (gdeg) {
        float dg = gdeg[g];
        sc = (dg > 0.f) ? 1.0f / dg : 0.f;
    }
    float4 v = *(const float4*)(srcbuf + (size_t)g * DD + lane * 4);
    float* p = dst + (size_t)s * DD + lane * 4;
    atomicAdd(p + 0, v.x * sc);
    atomicAdd(p + 1, v.y * sc);
    atomicAdd(p + 2, v.z * sc);
    atomicAdd(p + 3, v.w * sc);
}

// ---------------- pointwise: h = prelu(h * d_inv[n] + b) (in place) ----------------
__global__ __launch_bounds__(256) void k_pw_mid(float* __restrict__ h,
                                                const float* __restrict__ deg_n,
                                                const float* __restrict__ bias,
                                                const float* __restrict__ aP) {
    int t = blockIdx.x * 256 + threadIdx.x;
    const int TOT = NN * (DD / 4);
    if (t >= TOT) return;
    int n = t >> 6;   // DD/4 == 64
    int c = t & 63;
    float dg = deg_n[n];
    float dinv = (dg > 0.f) ? 1.f / dg : 0.f;
    float a = *aP;
    float4 v  = ((const float4*)h)[t];
    float4 bb = ((const float4*)bias)[c];
    float4 r;
    r.x = v.x * dinv + bb.x; r.x = (r.x >= 0.f) ? r.x : a * r.x;
    r.y = v.y * dinv + bb.y; r.y = (r.y >= 0.f) ? r.y : a * r.y;
    r.z = v.z * dinv + bb.z; r.z = (r.z >= 0.f) ? r.z : a * r.z;
    r.w = v.w * dinv + bb.w; r.w = (r.w >= 0.f) ? r.w : a * r.w;
    ((float4*)h)[t] = r;
}

// ---------------- final pointwise: out = prelu(acc * d_inv[n] + b + x) ----------------
__global__ __launch_bounds__(256) void k_pw_final(const float* __restrict__ acc,
                                                  const float* __restrict__ x,
                                                  const float* __restrict__ deg_n,
                                                  const float* __restrict__ bias,
                                                  const float* __restrict__ aP,
                                                  float* __restrict__ out) {
    int t = blockIdx.x * 256 + threadIdx.x;
    const int TOT = NN * (DD / 4);
    if (t >= TOT) return;
    int n = t >> 6;
    int c = t & 63;
    float dg = deg_n[n];
    float dinv = (dg > 0.f) ? 1.f / dg : 0.f;
    float a = *aP;
    float4 v  = ((const float4*)acc)[t];
    float4 xv = ((const float4*)x)[t];
    float4 bb = ((const float4*)bias)[c];
    float4 r;
    r.x = v.x * dinv + bb.x + xv.x; r.x = (r.x >= 0.f) ? r.x : a * r.x;
    r.y = v.y * dinv + bb.y + xv.y; r.y = (r.y >= 0.f) ? r.y : a * r.y;
    r.z = v.z * dinv + bb.z + xv.z; r.z = (r.z >= 0.f) ? r.z : a * r.z;
    r.w = v.w * dinv + bb.w + xv.w; r.w = (r.w >= 0.f) ? r.w : a * r.w;
    ((float4*)out)[t] = r;
}

extern "C" void kernel_launch(void* const* d_in, const int* in_sizes, int n_in,
                              void* d_out, int out_size, void* d_ws, size_t ws_size,
                              hipStream_t stream) {
    const float* x       = (const float*)d_in[0];
    const float* W1      = (const float*)d_in[1];
    const float* b1      = (const float*)d_in[2];
    const float* W2      = (const float*)d_in[3];
    const float* b2      = (const float*)d_in[4];
    const float* prelu_a = (const float*)d_in[5];
    const int*   hei     = (const int*)d_in[6];
    const int* idx_src = hei;          // hei[0,:] node indices
    const int* idx_he  = hei + NEDGE;  // hei[1,:] hyperedge indices

    float* out   = (float*)d_out;
    float* A     = (float*)d_ws;                 // [50000, 256] scratch
    float* deg_n = A + (size_t)NN * DD;          // [50000]
    float* deg_e = deg_n + NN;                   // [50000]

    const size_t BIG = sizeof(float) * (size_t)NN * DD;  // NN == NHE

    // degrees (shared by both layers)
    hipMemsetAsync(deg_n, 0, sizeof(float) * (NN + NHE), stream);
    k_degrees<<<(NEDGE + 255) / 256, 256, 0, stream>>>(idx_src, idx_he, deg_n, deg_e);

    dim3 ggrid((NN + 63) / 64, DD / 64);
    const int sblocks = (NEDGE * 64) / 256;   // 80000
    const int pblocks = (NN * (DD / 4) + 255) / 256;

    // ---- layer 1 ----
    k_gemm_nt<<<ggrid, 256, 0, stream>>>(x, W1, out, NN);              // out = x@W1^T
    hipMemsetAsync(A, 0, BIG, stream);
    k_scatter<<<sblocks, 256, 0, stream>>>(out, A, idx_src, idx_he, nullptr);  // A = ef1 (raw)
    hipMemsetAsync(out, 0, BIG, stream);
    k_scatter<<<sblocks, 256, 0, stream>>>(A, out, idx_he, idx_src, deg_e);    // out = sum ef1*b_inv
    k_pw_mid<<<pblocks, 256, 0, stream>>>(out, deg_n, b1, prelu_a);            // out = h1

    // ---- layer 2 ----
    k_gemm_nt<<<ggrid, 256, 0, stream>>>(out, W2, A, NN);              // A = h1@W2^T
    hipMemsetAsync(out, 0, BIG, stream);
    k_scatter<<<sblocks, 256, 0, stream>>>(A, out, idx_src, idx_he, nullptr);  // out = ef2 (raw)
    hipMemsetAsync(A, 0, BIG, stream);
    k_scatter<<<sblocks, 256, 0, stream>>>(out, A, idx_he, idx_src, deg_e);    // A = sum ef2*b_inv
    k_pw_final<<<pblocks, 256, 0, stream>>>(A, x, deg_n, b2, prelu_a, out);    // out = prelu(... + x)
}

// Round 2
// 743.006 us; speedup vs baseline: 6.2659x; 6.2659x over previous
//
#include <hip/hip_runtime.h>

#define NN    50000   // nodes
#define NHE   50000   // hyperedges
#define NEDGE 320000  // incidence pairs
#define DD    256     // feature dim

// ---------------- CSR build: counting sort, no big atomics ----------------
__global__ __launch_bounds__(256) void k_count(const int* __restrict__ src,
                                               const int* __restrict__ he,
                                               int* __restrict__ cnt_n,
                                               int* __restrict__ cnt_e) {
    int e = blockIdx.x * 256 + threadIdx.x;
    if (e >= NEDGE) return;
    atomicAdd(&cnt_n[src[e]], 1);
    atomicAdd(&cnt_e[he[e]], 1);
}

// single-workgroup exclusive scan (n ~ 50000): off[0..n], off[n] = total
__global__ __launch_bounds__(256) void k_scan(const int* __restrict__ cnt,
                                              int* __restrict__ off, int n) {
    const int T = 256;
    int chunk = (n + T - 1) / T;
    int t = threadIdx.x;
    int s = t * chunk, e = min(s + chunk, n);
    int sum = 0;
    for (int i = s; i < e; ++i) sum += cnt[i];
    __shared__ int part[T];
    __shared__ int partx[T + 1];
    part[t] = sum;
    __syncthreads();
    if (t == 0) {
        int r = 0;
        for (int i = 0; i < T; ++i) { partx[i] = r; r += part[i]; }
        partx[T] = r;
    }
    __syncthreads();
    int r = partx[t];
    for (int i = s; i < e; ++i) { off[i] = r; r += cnt[i]; }
    if (t == 0) off[n] = partx[T];
}

// fill adjacency: adj_n = hyperedge endpoints grouped by node,
//                 adj_e = node endpoints grouped by hyperedge
__global__ __launch_bounds__(256) void k_fill(const int* __restrict__ src,
                                              const int* __restrict__ he,
                                              const int* __restrict__ off_n,
                                              const int* __restrict__ off_e,
                                              int* __restrict__ cur_n,
                                              int* __restrict__ cur_e,
                                              int* __restrict__ adj_n,
                                              int* __restrict__ adj_e) {
    int e = blockIdx.x * 256 + threadIdx.x;
    if (e >= NEDGE) return;
    int s = src[e], h = he[e];
    int pn = off_n[s] + atomicAdd(&cur_n[s], 1);
    adj_n[pn] = h;
    int pe = off_e[h] + atomicAdd(&cur_e[h], 1);
    adj_e[pe] = s;
}

// ---------------- tiled fp32 GEMM: C[m,n] = sum_k A[m,k] * W[n,k] ----------------
__global__ __launch_bounds__(256) void k_gemm_nt(const float* __restrict__ A,
                                                 const float* __restrict__ W,
                                                 float* __restrict__ C, int M) {
    __shared__ float As[16][68];
    __shared__ float Ws[16][68];
    const int t    = threadIdx.x;
    const int m0   = blockIdx.x * 64;
    const int n0   = blockIdx.y * 64;
    const int lrow = t >> 2;
    const int lcol = (t & 3) << 2;
    const int ty   = t >> 4;
    const int tx   = t & 15;

    float acc[4][4] = {{0.f}};

    const int gm = m0 + lrow;
    const float* Arow = A + (size_t)gm * DD;
    const float* Wrow = W + (size_t)(n0 + lrow) * DD;

    for (int k0 = 0; k0 < DD; k0 += 16) {
        float4 av = make_float4(0.f, 0.f, 0.f, 0.f);
        if (gm < M) av = *(const float4*)(Arow + k0 + lcol);
        float4 wv = *(const float4*)(Wrow + k0 + lcol);
        __syncthreads();
        As[lcol + 0][lrow] = av.x;
        As[lcol + 1][lrow] = av.y;
        As[lcol + 2][lrow] = av.z;
        As[lcol + 3][lrow] = av.w;
        Ws[lcol + 0][lrow] = wv.x;
        Ws[lcol + 1][lrow] = wv.y;
        Ws[lcol + 2][lrow] = wv.z;
        Ws[lcol + 3][lrow] = wv.w;
        __syncthreads();
#pragma unroll
        for (int kk = 0; kk < 16; ++kk) {
            float4 af = *(const float4*)&As[kk][ty * 4];
            float4 bf = *(const float4*)&Ws[kk][tx * 4];
            const float aarr[4] = {af.x, af.y, af.z, af.w};
            const float barr[4] = {bf.x, bf.y, bf.z, bf.w};
#pragma unroll
            for (int i = 0; i < 4; ++i)
#pragma unroll
                for (int j = 0; j < 4; ++j)
                    acc[i][j] = fmaf(aarr[i], barr[j], acc[i][j]);
        }
    }
#pragma unroll
    for (int i = 0; i < 4; ++i) {
        int gmo = m0 + ty * 4 + i;
        if (gmo < M) {
            float4 v = make_float4(acc[i][0], acc[i][1], acc[i][2], acc[i][3]);
            *(float4*)(C + (size_t)gmo * DD + n0 + tx * 4) = v;
        }
    }
}

// ---------------- gather into hyperedges: ef[h] = (1/deg) * sum xw[adj] ----------------
// one wave (64 lanes) per destination row; float4 per lane
__global__ __launch_bounds__(256) void k_gather_edge(const float* __restrict__ xw,
                                                     float* __restrict__ ef,
                                                     const int* __restrict__ off,
                                                     const int* __restrict__ adj) {
    int w = (blockIdx.x * 256 + threadIdx.x) >> 6;
    int lane = threadIdx.x & 63;
    if (w >= NHE) return;
    int b = off[w], e = off[w + 1];
    float4 acc = make_float4(0.f, 0.f, 0.f, 0.f);
    for (int i = b; i < e; ++i) {
        int g = adj[i];
        float4 v = *(const float4*)(xw + (size_t)g * DD + lane * 4);
        acc.x += v.x; acc.y += v.y; acc.z += v.z; acc.w += v.w;
    }
    float sc = (e > b) ? 1.f / (float)(e - b) : 0.f;
    acc.x *= sc; acc.y *= sc; acc.z *= sc; acc.w *= sc;
    *(float4*)(ef + (size_t)w * DD + lane * 4) = acc;
}

// ---------------- gather into nodes + mid epilogue: h = prelu(sum/deg + b) ----------------
__global__ __launch_bounds__(256) void k_gather_node_mid(const float* __restrict__ ef,
                                                         float* __restrict__ h,
                                                         const int* __restrict__ off,
                                                         const int* __restrict__ adj,
                                                         const float* __restrict__ bias,
                                                         const float* __restrict__ aP) {
    int w = (blockIdx.x * 256 + threadIdx.x) >> 6;
    int lane = threadIdx.x & 63;
    if (w >= NN) return;
    int b = off[w], e = off[w + 1];
    float4 acc = make_float4(0.f, 0.f, 0.f, 0.f);
    for (int i = b; i < e; ++i) {
        int g = adj[i];
        float4 v = *(const float4*)(ef + (size_t)g * DD + lane * 4);
        acc.x += v.x; acc.y += v.y; acc.z += v.z; acc.w += v.w;
    }
    float sc = (e > b) ? 1.f / (float)(e - b) : 0.f;
    float a = *aP;
    float4 bb = ((const float4*)bias)[lane];
    float4 r;
    r.x = acc.x * sc + bb.x; r.x = (r.x >= 0.f) ? r.x : a * r.x;
    r.y = acc.y * sc + bb.y; r.y = (r.y >= 0.f) ? r.y : a * r.y;
    r.z = acc.z * sc + bb.z; r.z = (r.z >= 0.f) ? r.z : a * r.z;
    r.w = acc.w * sc + bb.w; r.w = (r.w >= 0.f) ? r.w : a * r.w;
    *(float4*)(h + (size_t)w * DD + lane * 4) = r;
}

// ---------------- gather into nodes + final epilogue: out = prelu(sum/deg + b + x) ----------------
__global__ __launch_bounds__(256) void k_gather_node_final(const float* __restrict__ ef,
                                                           const float* __restrict__ x,
                                                           float* __restrict__ out,
                                                           const int* __restrict__ off,
                                                           const int* __restrict__ adj,
                                                           const float* __restrict__ bias,
                                                           const float* __restrict__ aP) {
    int w = (blockIdx.x * 256 + threadIdx.x) >> 6;
    int lane = threadIdx.x & 63;
    if (w >= NN) return;
    int b = off[w], e = off[w + 1];
    float4 acc = make_float4(0.f, 0.f, 0.f, 0.f);
    for (int i = b; i < e; ++i) {
        int g = adj[i];
        float4 v = *(const float4*)(ef + (size_t)g * DD + lane * 4);
        acc.x += v.x; acc.y += v.y; acc.z += v.z; acc.w += v.w;
    }
    float sc = (e > b) ? 1.f / (float)(e - b) : 0.f;
    float a = *aP;
    float4 bb = ((const float4*)bias)[lane];
    float4 xv = *(const float4*)(x + (size_t)w * DD + lane * 4);
    float4 r;
    r.x = acc.x * sc + bb.x + xv.x; r.x = (r.x >= 0.f) ? r.x : a * r.x;
    r.y = acc.y * sc + bb.y + xv.y; r.y = (r.y >= 0.f) ? r.y : a * r.y;
    r.z = acc.z * sc + bb.z + xv.z; r.z = (r.z >= 0.f) ? r.z : a * r.z;
    r.w = acc.w * sc + bb.w + xv.w; r.w = (r.w >= 0.f) ? r.w : a * r.w;
    *(float4*)(out + (size_t)w * DD + lane * 4) = r;
}

extern "C" void kernel_launch(void* const* d_in, const int* in_sizes, int n_in,
                              void* d_out, int out_size, void* d_ws, size_t ws_size,
                              hipStream_t stream) {
    const float* x       = (const float*)d_in[0];
    const float* W1      = (const float*)d_in[1];
    const float* b1      = (const float*)d_in[2];
    const float* W2      = (const float*)d_in[3];
    const float* b2      = (const float*)d_in[4];
    const float* prelu_a = (const float*)d_in[5];
    const int*   hei     = (const int*)d_in[6];
    const int* idx_src = hei;          // hei[0,:] node indices
    const int* idx_he  = hei + NEDGE;  // hei[1,:] hyperedge indices

    float* out = (float*)d_out;
    float* A   = (float*)d_ws;                       // [NN, DD] ping-pong buffer
    int* off_n = (int*)(A + (size_t)NN * DD);        // NN+1
    int* off_e = off_n + NN + 1;                     // NHE+1
    int* cur_n = off_e + NHE + 1;                    // NN   (doubles as counts)
    int* cur_e = cur_n + NN;                         // NHE
    int* adj_n = cur_e + NHE;                        // NEDGE (hyperedge endpoints, grouped by node)
    int* adj_e = adj_n + NEDGE;                      // NEDGE (node endpoints, grouped by hyperedge)

    const int eblocks = (NEDGE + 255) / 256;
    const int gblocks = (NN * 64 + 255) / 256;       // one wave per row, NN == NHE
    dim3 ggrid((NN + 63) / 64, DD / 64);

    // ---- CSR build ----
    hipMemsetAsync(cur_n, 0, sizeof(int) * (NN + NHE), stream);
    k_count<<<eblocks, 256, 0, stream>>>(idx_src, idx_he, cur_n, cur_e);
    k_scan<<<1, 256, 0, stream>>>(cur_n, off_n, NN);
    k_scan<<<1, 256, 0, stream>>>(cur_e, off_e, NHE);
    hipMemsetAsync(cur_n, 0, sizeof(int) * (NN + NHE), stream);
    k_fill<<<eblocks, 256, 0, stream>>>(idx_src, idx_he, off_n, off_e,
                                        cur_n, cur_e, adj_n, adj_e);

    // ---- layer 1 ----
    k_gemm_nt<<<ggrid, 256, 0, stream>>>(x, W1, A, NN);                 // A = x@W1^T
    k_gather_edge<<<gblocks, 256, 0, stream>>>(A, out, off_e, adj_e);   // out = ef1
    k_gather_node_mid<<<gblocks, 256, 0, stream>>>(out, A, off_n, adj_n, b1, prelu_a);  // A = h1

    // ---- layer 2 ----
    k_gemm_nt<<<ggrid, 256, 0, stream>>>(A, W2, out, NN);               // out = h1@W2^T
    k_gather_edge<<<gblocks, 256, 0, stream>>>(out, A, off_e, adj_e);   // A = ef2
    k_gather_node_final<<<gblocks, 256, 0, stream>>>(A, x, out, off_n, adj_n, b2, prelu_a);
}

// Round 3
// 562.181 us; speedup vs baseline: 8.2813x; 1.3216x over previous
//
#include <hip/hip_runtime.h>

#define NN    50000   // nodes
#define NHE   50000   // hyperedges
#define NEDGE 320000  // incidence pairs
#define DD    256     // feature dim

typedef float f32x4 __attribute__((ext_vector_type(4)));
typedef short short8 __attribute__((ext_vector_type(8)));

// ---- bf16 helpers (RTNE) ----
static __device__ __forceinline__ unsigned short f2b(float f) {
    union { float f; unsigned u; } c; c.f = f;
    unsigned u = c.u;
    u += 0x7fffu + ((u >> 16) & 1u);
    return (unsigned short)(u >> 16);
}
static __device__ __forceinline__ float b2f_lo(unsigned v) {
    union { unsigned u; float f; } c; c.u = v << 16; return c.f;
}
static __device__ __forceinline__ float b2f_hi(unsigned v) {
    union { unsigned u; float f; } c; c.u = v & 0xffff0000u; return c.f;
}
static __device__ __forceinline__ unsigned pack2(float a, float b) {
    return (unsigned)f2b(a) | ((unsigned)f2b(b) << 16);
}

// ---------------- CSR build ----------------
__global__ __launch_bounds__(256) void k_count(const int* __restrict__ src,
                                               const int* __restrict__ he,
                                               int* __restrict__ cnt_n,
                                               int* __restrict__ cnt_e) {
    int e = blockIdx.x * 256 + threadIdx.x;
    if (e >= NEDGE) return;
    atomicAdd(&cnt_n[src[e]], 1);
    atomicAdd(&cnt_e[he[e]], 1);
}

__global__ __launch_bounds__(256) void k_scan(const int* __restrict__ cnt,
                                              int* __restrict__ off, int n) {
    const int T = 256;
    int chunk = (n + T - 1) / T;
    int t = threadIdx.x;
    int s = t * chunk, e = min(s + chunk, n);
    int sum = 0;
    for (int i = s; i < e; ++i) sum += cnt[i];
    __shared__ int part[T];
    __shared__ int partx[T + 1];
    part[t] = sum;
    __syncthreads();
    if (t == 0) {
        int r = 0;
        for (int i = 0; i < T; ++i) { partx[i] = r; r += part[i]; }
        partx[T] = r;
    }
    __syncthreads();
    int r = partx[t];
    for (int i = s; i < e; ++i) { off[i] = r; r += cnt[i]; }
    if (t == 0) off[n] = partx[T];
}

__global__ __launch_bounds__(256) void k_fill(const int* __restrict__ src,
                                              const int* __restrict__ he,
                                              const int* __restrict__ off_n,
                                              const int* __restrict__ off_e,
                                              int* __restrict__ cur_n,
                                              int* __restrict__ cur_e,
                                              int* __restrict__ adj_n,
                                              int* __restrict__ adj_e) {
    int e = blockIdx.x * 256 + threadIdx.x;
    if (e >= NEDGE) return;
    int s = src[e], h = he[e];
    int pn = off_n[s] + atomicAdd(&cur_n[s], 1);
    adj_n[pn] = h;
    int pe = off_e[h] + atomicAdd(&cur_e[h], 1);
    adj_e[pe] = s;
}

// ---------------- fp32 -> bf16 convert (4 elems/thread) ----------------
__global__ __launch_bounds__(256) void k_cvt(const float* __restrict__ s,
                                             unsigned short* __restrict__ d, int n4) {
    int t = blockIdx.x * 256 + threadIdx.x;
    if (t >= n4) return;
    float4 v = ((const float4*)s)[t];
    uint2 o;
    o.x = pack2(v.x, v.y);
    o.y = pack2(v.z, v.w);
    ((uint2*)d)[t] = o;
}

// ---------------- bf16 MFMA GEMM: C[m,n] = sum_k A[m,k]*W[n,k], all bf16, fp32 acc ----
// Block: 256 thr (4 waves, 2x2 of 64x64 wave tiles), tile 128x128, BK=32, K=256.
// LDS XOR swizzle: elem (row r, 8-elem seg s) at ushort offset r*32 + (s^(r&3))*8.
__global__ __launch_bounds__(256) void k_gemm_bf16(const unsigned short* __restrict__ Ab,
                                                   const unsigned short* __restrict__ Wb,
                                                   unsigned short* __restrict__ Cb, int M) {
    __shared__ __align__(16) unsigned short As[128 * 32];
    __shared__ __align__(16) unsigned short Bs[128 * 32];
    const int t    = threadIdx.x;
    const int m0   = blockIdx.x * 128;
    const int n0   = blockIdx.y * 128;
    const int lane = t & 63;
    const int wave = t >> 6;
    const int wm   = (wave >> 1) * 64;
    const int wn   = (wave & 1) * 64;
    const int fr   = lane & 15;   // fragment row
    const int fq   = lane >> 4;   // quad

    f32x4 acc[4][4] = {};

    const int sr = t >> 2;   // staging row 0..63 (and +64)
    const int ss = t & 3;    // staging 8-elem segment

    for (int k0 = 0; k0 < DD; k0 += 32) {
        __syncthreads();
#pragma unroll
        for (int i = 0; i < 2; ++i) {
            int r  = sr + i * 64;
            int gm = m0 + r;
            uint4 av = make_uint4(0u, 0u, 0u, 0u);
            if (gm < M) av = *(const uint4*)(Ab + (size_t)gm * DD + k0 + ss * 8);
            *(uint4*)(As + r * 32 + ((ss ^ (r & 3)) * 8)) = av;
            uint4 bv = *(const uint4*)(Wb + (size_t)(n0 + r) * DD + k0 + ss * 8);
            *(uint4*)(Bs + r * 32 + ((ss ^ (r & 3)) * 8)) = bv;
        }
        __syncthreads();

        short8 af[4], bf[4];
#pragma unroll
        for (int mt = 0; mt < 4; ++mt) {
            int r = wm + mt * 16 + fr;
            af[mt] = *(const short8*)(As + r * 32 + ((fq ^ (r & 3)) * 8));
        }
#pragma unroll
        for (int nt = 0; nt < 4; ++nt) {
            int r = wn + nt * 16 + fr;
            bf[nt] = *(const short8*)(Bs + r * 32 + ((fq ^ (r & 3)) * 8));
        }
#pragma unroll
        for (int mt = 0; mt < 4; ++mt)
#pragma unroll
            for (int nt = 0; nt < 4; ++nt)
                acc[mt][nt] = __builtin_amdgcn_mfma_f32_16x16x32_bf16(af[mt], bf[nt],
                                                                      acc[mt][nt], 0, 0, 0);
    }

    // C/D layout: col = lane&15, row = quad*4 + reg   [verified m89]
#pragma unroll
    for (int mt = 0; mt < 4; ++mt) {
#pragma unroll
        for (int i = 0; i < 4; ++i) {
            int gm = m0 + wm + mt * 16 + fq * 4 + i;
            if (gm >= M) continue;
#pragma unroll
            for (int nt = 0; nt < 4; ++nt) {
                int gn = n0 + wn + nt * 16 + fr;
                Cb[(size_t)gm * DD + gn] = f2b(acc[mt][nt][i]);
            }
        }
    }
}

// ---------------- gather kernels (bf16 rows, fp32 accumulate) ----------------
// one wave per destination row, 4 bf16 (8B) per lane
__global__ __launch_bounds__(256) void k_gather_edge_b(const unsigned short* __restrict__ xw,
                                                       unsigned short* __restrict__ ef,
                                                       const int* __restrict__ off,
                                                       const int* __restrict__ adj) {
    int w = (blockIdx.x * 256 + threadIdx.x) >> 6;
    int lane = threadIdx.x & 63;
    if (w >= NHE) return;
    int b = off[w], e = off[w + 1];
    float a0 = 0.f, a1 = 0.f, a2 = 0.f, a3 = 0.f;
    for (int i = b; i < e; ++i) {
        int g = adj[i];
        uint2 v = *(const uint2*)(xw + (size_t)g * DD + lane * 4);
        a0 += b2f_lo(v.x); a1 += b2f_hi(v.x);
        a2 += b2f_lo(v.y); a3 += b2f_hi(v.y);
    }
    float sc = (e > b) ? 1.f / (float)(e - b) : 0.f;
    uint2 o;
    o.x = pack2(a0 * sc, a1 * sc);
    o.y = pack2(a2 * sc, a3 * sc);
    *(uint2*)(ef + (size_t)w * DD + lane * 4) = o;
}

__global__ __launch_bounds__(256) void k_gather_node_mid_b(const unsigned short* __restrict__ ef,
                                                           unsigned short* __restrict__ h,
                                                           const int* __restrict__ off,
                                                           const int* __restrict__ adj,
                                                           const float* __restrict__ bias,
                                                           const float* __restrict__ aP) {
    int w = (blockIdx.x * 256 + threadIdx.x) >> 6;
    int lane = threadIdx.x & 63;
    if (w >= NN) return;
    int b = off[w], e = off[w + 1];
    float a0 = 0.f, a1 = 0.f, a2 = 0.f, a3 = 0.f;
    for (int i = b; i < e; ++i) {
        int g = adj[i];
        uint2 v = *(const uint2*)(ef + (size_t)g * DD + lane * 4);
        a0 += b2f_lo(v.x); a1 += b2f_hi(v.x);
        a2 += b2f_lo(v.y); a3 += b2f_hi(v.y);
    }
    float sc = (e > b) ? 1.f / (float)(e - b) : 0.f;
    float a = *aP;
    float4 bb = ((const float4*)bias)[lane];
    float r0 = a0 * sc + bb.x; r0 = (r0 >= 0.f) ? r0 : a * r0;
    float r1 = a1 * sc + bb.y; r1 = (r1 >= 0.f) ? r1 : a * r1;
    float r2 = a2 * sc + bb.z; r2 = (r2 >= 0.f) ? r2 : a * r2;
    float r3 = a3 * sc + bb.w; r3 = (r3 >= 0.f) ? r3 : a * r3;
    uint2 o;
    o.x = pack2(r0, r1);
    o.y = pack2(r2, r3);
    *(uint2*)(h + (size_t)w * DD + lane * 4) = o;
}

__global__ __launch_bounds__(256) void k_gather_node_final_b(const unsigned short* __restrict__ ef,
                                                             const float* __restrict__ x,
                                                             float* __restrict__ out,
                                                             const int* __restrict__ off,
                                                             const int* __restrict__ adj,
                                                             const float* __restrict__ bias,
                                                             const float* __restrict__ aP) {
    int w = (blockIdx.x * 256 + threadIdx.x) >> 6;
    int lane = threadIdx.x & 63;
    if (w >= NN) return;
    int b = off[w], e = off[w + 1];
    float a0 = 0.f, a1 = 0.f, a2 = 0.f, a3 = 0.f;
    for (int i = b; i < e; ++i) {
        int g = adj[i];
        uint2 v = *(const uint2*)(ef + (size_t)g * DD + lane * 4);
        a0 += b2f_lo(v.x); a1 += b2f_hi(v.x);
        a2 += b2f_lo(v.y); a3 += b2f_hi(v.y);
    }
    float sc = (e > b) ? 1.f / (float)(e - b) : 0.f;
    float a = *aP;
    float4 bb = ((const float4*)bias)[lane];
    float4 xv = *(const float4*)(x + (size_t)w * DD + lane * 4);
    float4 r;
    r.x = a0 * sc + bb.x + xv.x; r.x = (r.x >= 0.f) ? r.x : a * r.x;
    r.y = a1 * sc + bb.y + xv.y; r.y = (r.y >= 0.f) ? r.y : a * r.y;
    r.z = a2 * sc + bb.z + xv.z; r.z = (r.z >= 0.f) ? r.z : a * r.z;
    r.w = a3 * sc + bb.w + xv.w; r.w = (r.w >= 0.f) ? r.w : a * r.w;
    *(float4*)(out + (size_t)w * DD + lane * 4) = r;
}

extern "C" void kernel_launch(void* const* d_in, const int* in_sizes, int n_in,
                              void* d_out, int out_size, void* d_ws, size_t ws_size,
                              hipStream_t stream) {
    const float* x       = (const float*)d_in[0];
    const float* W1      = (const float*)d_in[1];
    const float* b1      = (const float*)d_in[2];
    const float* W2      = (const float*)d_in[3];
    const float* b2      = (const float*)d_in[4];
    const float* prelu_a = (const float*)d_in[5];
    const int*   hei     = (const int*)d_in[6];
    const int* idx_src = hei;          // hei[0,:] node indices
    const int* idx_he  = hei + NEDGE;  // hei[1,:] hyperedge indices

    float* out = (float*)d_out;
    // workspace: two bf16 feature buffers + CSR ints (same 54.56 MB as round 2)
    unsigned short* B1 = (unsigned short*)d_ws;           // [NN*DD] bf16
    unsigned short* B2 = B1 + (size_t)NN * DD;            // [NN*DD] bf16
    int* off_n = (int*)(B2 + (size_t)NN * DD);            // NN+1
    int* off_e = off_n + NN + 1;                          // NHE+1
    int* cur_n = off_e + NHE + 1;                         // NN (counts)
    int* cur_e = cur_n + NN;                              // NHE
    int* adj_n = cur_e + NHE;                             // NEDGE
    int* adj_e = adj_n + NEDGE;                           // NEDGE
    // d_out doubles as bf16(x) + bf16(W1/W2) until the final kernel
    unsigned short* xb  = (unsigned short*)d_out;         // [NN*DD] bf16 (25.6 MB)
    unsigned short* w1b = xb + (size_t)NN * DD;           // [DD*DD]
    unsigned short* w2b = w1b + DD * DD;                  // [DD*DD]

    const int eblocks = (NEDGE + 255) / 256;
    const int gblocks = (NN * 64 + 255) / 256;
    dim3 ggrid((NN + 127) / 128, DD / 128);

    // ---- CSR build ----
    hipMemsetAsync(cur_n, 0, sizeof(int) * (NN + NHE), stream);
    k_count<<<eblocks, 256, 0, stream>>>(idx_src, idx_he, cur_n, cur_e);
    k_scan<<<1, 256, 0, stream>>>(cur_n, off_n, NN);
    k_scan<<<1, 256, 0, stream>>>(cur_e, off_e, NHE);
    hipMemsetAsync(cur_n, 0, sizeof(int) * (NN + NHE), stream);
    k_fill<<<eblocks, 256, 0, stream>>>(idx_src, idx_he, off_n, off_e,
                                        cur_n, cur_e, adj_n, adj_e);

    // ---- bf16 conversions ----
    k_cvt<<<(NN * DD / 4 + 255) / 256, 256, 0, stream>>>(x, xb, NN * DD / 4);
    k_cvt<<<(DD * DD / 4 + 255) / 256, 256, 0, stream>>>(W1, w1b, DD * DD / 4);
    k_cvt<<<(DD * DD / 4 + 255) / 256, 256, 0, stream>>>(W2, w2b, DD * DD / 4);

    // ---- layer 1 ----
    k_gemm_bf16<<<ggrid, 256, 0, stream>>>(xb, w1b, B1, NN);              // B1 = bf16(x@W1^T)
    k_gather_edge_b<<<gblocks, 256, 0, stream>>>(B1, B2, off_e, adj_e);   // B2 = ef1
    k_gather_node_mid_b<<<gblocks, 256, 0, stream>>>(B2, B1, off_n, adj_n, b1, prelu_a); // B1 = h1

    // ---- layer 2 ----
    k_gemm_bf16<<<ggrid, 256, 0, stream>>>(B1, w2b, B2, NN);              // B2 = bf16(h1@W2^T)
    k_gather_edge_b<<<gblocks, 256, 0, stream>>>(B2, B1, off_e, adj_e);   // B1 = ef2
    k_gather_node_final_b<<<gblocks, 256, 0, stream>>>(B1, x, out, off_n, adj_n, b2, prelu_a);
}

// Round 4
// 397.834 us; speedup vs baseline: 11.7024x; 1.4131x over previous
//
#include <hip/hip_runtime.h>

#define NN    50000   // nodes
#define NHE   50000   // hyperedges
#define NEDGE 320000  // incidence pairs
#define DD    256     // feature dim

#define SB    1024                    // scan elements per block
#define NBLK  ((NN + SB - 1) / SB)    // 49 blocks per segment (NN == NHE)

typedef float f32x4 __attribute__((ext_vector_type(4)));
typedef short short8 __attribute__((ext_vector_type(8)));

// ---- bf16 helpers (RTNE) ----
static __device__ __forceinline__ unsigned short f2b(float f) {
    union { float f; unsigned u; } c; c.f = f;
    unsigned u = c.u;
    u += 0x7fffu + ((u >> 16) & 1u);
    return (unsigned short)(u >> 16);
}
static __device__ __forceinline__ float b2f_lo(unsigned v) {
    union { unsigned u; float f; } c; c.u = v << 16; return c.f;
}
static __device__ __forceinline__ float b2f_hi(unsigned v) {
    union { unsigned u; float f; } c; c.u = v & 0xffff0000u; return c.f;
}
static __device__ __forceinline__ unsigned pack2(float a, float b) {
    return (unsigned)f2b(a) | ((unsigned)f2b(b) << 16);
}

// ---------------- CSR build ----------------
__global__ __launch_bounds__(256) void k_count(const int* __restrict__ src,
                                               const int* __restrict__ he,
                                               int* __restrict__ cnt_n,
                                               int* __restrict__ cnt_e) {
    int e = blockIdx.x * 256 + threadIdx.x;
    if (e >= NEDGE) return;
    atomicAdd(&cnt_n[src[e]], 1);
    atomicAdd(&cnt_e[he[e]], 1);
}

// ---- parallel scan, pass A: per-block sums (2 segments in one grid) ----
__global__ __launch_bounds__(256) void k_scan_a(const int* __restrict__ cnt_n,
                                                const int* __restrict__ cnt_e,
                                                int* __restrict__ bsum) {
    int b   = blockIdx.x;            // 0 .. 2*NBLK-1
    int seg = b / NBLK, lb = b % NBLK;
    const int* cnt = seg ? cnt_e : cnt_n;
    int t = threadIdx.x;
    int idx = lb * SB + t * 4;
    int s = 0;
#pragma unroll
    for (int j = 0; j < 4; ++j)
        if (idx + j < NN) s += cnt[idx + j];
    __shared__ int red[256];
    red[t] = s;
    __syncthreads();
    for (int o = 128; o > 0; o >>= 1) {
        if (t < o) red[t] += red[t + o];
        __syncthreads();
    }
    if (t == 0) bsum[b] = red[0];
}

// ---- pass B: scan the 2*NBLK block sums (tiny) ----
__global__ __launch_bounds__(64) void k_scan_b(const int* __restrict__ bsum,
                                               int* __restrict__ bbase) {
    if (threadIdx.x == 0) {
        int r = 0;
        for (int i = 0; i < NBLK; ++i) { bbase[i] = r; r += bsum[i]; }
        bbase[2 * NBLK] = r;                       // total seg0 (== NEDGE)
        r = 0;
        for (int i = NBLK; i < 2 * NBLK; ++i) { bbase[i] = r; r += bsum[i]; }
        bbase[2 * NBLK + 1] = r;                   // total seg1 (== NEDGE)
    }
}

// ---- pass C: per-block exclusive scan + base, write offsets ----
__global__ __launch_bounds__(256) void k_scan_c(const int* __restrict__ cnt_n,
                                                const int* __restrict__ cnt_e,
                                                const int* __restrict__ bbase,
                                                int* __restrict__ off_n,
                                                int* __restrict__ off_e) {
    int b   = blockIdx.x;
    int seg = b / NBLK, lb = b % NBLK;
    const int* cnt = seg ? cnt_e : cnt_n;
    int* off = seg ? off_e : off_n;
    int t = threadIdx.x;
    int idx = lb * SB + t * 4;
    int v[4];
    int tsum = 0;
#pragma unroll
    for (int j = 0; j < 4; ++j) {
        v[j] = (idx + j < NN) ? cnt[idx + j] : 0;
        tsum += v[j];
    }
    __shared__ int sc[256];
    sc[t] = tsum;
    __syncthreads();
    for (int o = 1; o < 256; o <<= 1) {
        int val = (t >= o) ? sc[t - o] : 0;
        __syncthreads();
        sc[t] += val;
        __syncthreads();
    }
    int p = bbase[b] + sc[t] - tsum;   // exclusive prefix for this thread
#pragma unroll
    for (int j = 0; j < 4; ++j) {
        if (idx + j < NN) off[idx + j] = p;
        p += v[j];
    }
    if (b == 0 && t == 0) off_n[NN] = bbase[2 * NBLK];
    if (b == NBLK && t == 0) off_e[NHE] = bbase[2 * NBLK + 1];
}

__global__ __launch_bounds__(256) void k_fill(const int* __restrict__ src,
                                              const int* __restrict__ he,
                                              const int* __restrict__ off_n,
                                              const int* __restrict__ off_e,
                                              int* __restrict__ cur_n,
                                              int* __restrict__ cur_e,
                                              int* __restrict__ adj_n,
                                              int* __restrict__ adj_e) {
    int e = blockIdx.x * 256 + threadIdx.x;
    if (e >= NEDGE) return;
    int s = src[e], h = he[e];
    int pn = off_n[s] + atomicAdd(&cur_n[s], 1);
    adj_n[pn] = h;
    int pe = off_e[h] + atomicAdd(&cur_e[h], 1);
    adj_e[pe] = s;
}

// ---------------- fp32 -> bf16 convert (4 elems/thread) ----------------
__global__ __launch_bounds__(256) void k_cvt(const float* __restrict__ s,
                                             unsigned short* __restrict__ d, int n4) {
    int t = blockIdx.x * 256 + threadIdx.x;
    if (t >= n4) return;
    float4 v = ((const float4*)s)[t];
    uint2 o;
    o.x = pack2(v.x, v.y);
    o.y = pack2(v.z, v.w);
    ((uint2*)d)[t] = o;
}

// ---------------- bf16 MFMA GEMM: C[m,n] = sum_k A[m,k]*W[n,k] ----------------
__global__ __launch_bounds__(256) void k_gemm_bf16(const unsigned short* __restrict__ Ab,
                                                   const unsigned short* __restrict__ Wb,
                                                   unsigned short* __restrict__ Cb, int M) {
    __shared__ __align__(16) unsigned short As[128 * 32];
    __shared__ __align__(16) unsigned short Bs[128 * 32];
    const int t    = threadIdx.x;
    const int m0   = blockIdx.x * 128;
    const int n0   = blockIdx.y * 128;
    const int lane = t & 63;
    const int wave = t >> 6;
    const int wm   = (wave >> 1) * 64;
    const int wn   = (wave & 1) * 64;
    const int fr   = lane & 15;
    const int fq   = lane >> 4;

    f32x4 acc[4][4] = {};

    const int sr = t >> 2;
    const int ss = t & 3;

    for (int k0 = 0; k0 < DD; k0 += 32) {
        __syncthreads();
#pragma unroll
        for (int i = 0; i < 2; ++i) {
            int r  = sr + i * 64;
            int gm = m0 + r;
            uint4 av = make_uint4(0u, 0u, 0u, 0u);
            if (gm < M) av = *(const uint4*)(Ab + (size_t)gm * DD + k0 + ss * 8);
            *(uint4*)(As + r * 32 + ((ss ^ (r & 3)) * 8)) = av;
            uint4 bv = *(const uint4*)(Wb + (size_t)(n0 + r) * DD + k0 + ss * 8);
            *(uint4*)(Bs + r * 32 + ((ss ^ (r & 3)) * 8)) = bv;
        }
        __syncthreads();

        short8 af[4], bf[4];
#pragma unroll
        for (int mt = 0; mt < 4; ++mt) {
            int r = wm + mt * 16 + fr;
            af[mt] = *(const short8*)(As + r * 32 + ((fq ^ (r & 3)) * 8));
        }
#pragma unroll
        for (int nt = 0; nt < 4; ++nt) {
            int r = wn + nt * 16 + fr;
            bf[nt] = *(const short8*)(Bs + r * 32 + ((fq ^ (r & 3)) * 8));
        }
#pragma unroll
        for (int mt = 0; mt < 4; ++mt)
#pragma unroll
            for (int nt = 0; nt < 4; ++nt)
                acc[mt][nt] = __builtin_amdgcn_mfma_f32_16x16x32_bf16(af[mt], bf[nt],
                                                                      acc[mt][nt], 0, 0, 0);
    }

    // C/D layout: col = lane&15, row = quad*4 + reg
#pragma unroll
    for (int mt = 0; mt < 4; ++mt) {
#pragma unroll
        for (int i = 0; i < 4; ++i) {
            int gm = m0 + wm + mt * 16 + fq * 4 + i;
            if (gm >= M) continue;
#pragma unroll
            for (int nt = 0; nt < 4; ++nt) {
                int gn = n0 + wn + nt * 16 + fr;
                Cb[(size_t)gm * DD + gn] = f2b(acc[mt][nt][i]);
            }
        }
    }
}

// ---------------- gather kernels (bf16 rows, fp32 accumulate) ----------------
__global__ __launch_bounds__(256) void k_gather_edge_b(const unsigned short* __restrict__ xw,
                                                       unsigned short* __restrict__ ef,
                                                       const int* __restrict__ off,
                                                       const int* __restrict__ adj) {
    int w = (blockIdx.x * 256 + threadIdx.x) >> 6;
    int lane = threadIdx.x & 63;
    if (w >= NHE) return;
    int b = off[w], e = off[w + 1];
    float a0 = 0.f, a1 = 0.f, a2 = 0.f, a3 = 0.f;
    for (int i = b; i < e; ++i) {
        int g = adj[i];
        uint2 v = *(const uint2*)(xw + (size_t)g * DD + lane * 4);
        a0 += b2f_lo(v.x); a1 += b2f_hi(v.x);
        a2 += b2f_lo(v.y); a3 += b2f_hi(v.y);
    }
    float sc = (e > b) ? 1.f / (float)(e - b) : 0.f;
    uint2 o;
    o.x = pack2(a0 * sc, a1 * sc);
    o.y = pack2(a2 * sc, a3 * sc);
    *(uint2*)(ef + (size_t)w * DD + lane * 4) = o;
}

__global__ __launch_bounds__(256) void k_gather_node_mid_b(const unsigned short* __restrict__ ef,
                                                           unsigned short* __restrict__ h,
                                                           const int* __restrict__ off,
                                                           const int* __restrict__ adj,
                                                           const float* __restrict__ bias,
                                                           const float* __restrict__ aP) {
    int w = (blockIdx.x * 256 + threadIdx.x) >> 6;
    int lane = threadIdx.x & 63;
    if (w >= NN) return;
    int b = off[w], e = off[w + 1];
    float a0 = 0.f, a1 = 0.f, a2 = 0.f, a3 = 0.f;
    for (int i = b; i < e; ++i) {
        int g = adj[i];
        uint2 v = *(const uint2*)(ef + (size_t)g * DD + lane * 4);
        a0 += b2f_lo(v.x); a1 += b2f_hi(v.x);
        a2 += b2f_lo(v.y); a3 += b2f_hi(v.y);
    }
    float sc = (e > b) ? 1.f / (float)(e - b) : 0.f;
    float a = *aP;
    float4 bb = ((const float4*)bias)[lane];
    float r0 = a0 * sc + bb.x; r0 = (r0 >= 0.f) ? r0 : a * r0;
    float r1 = a1 * sc + bb.y; r1 = (r1 >= 0.f) ? r1 : a * r1;
    float r2 = a2 * sc + bb.z; r2 = (r2 >= 0.f) ? r2 : a * r2;
    float r3 = a3 * sc + bb.w; r3 = (r3 >= 0.f) ? r3 : a * r3;
    uint2 o;
    o.x = pack2(r0, r1);
    o.y = pack2(r2, r3);
    *(uint2*)(h + (size_t)w * DD + lane * 4) = o;
}

__global__ __launch_bounds__(256) void k_gather_node_final_b(const unsigned short* __restrict__ ef,
                                                             const float* __restrict__ x,
                                                             float* __restrict__ out,
                                                             const int* __restrict__ off,
                                                             const int* __restrict__ adj,
                                                             const float* __restrict__ bias,
                                                             const float* __restrict__ aP) {
    int w = (blockIdx.x * 256 + threadIdx.x) >> 6;
    int lane = threadIdx.x & 63;
    if (w >= NN) return;
    int b = off[w], e = off[w + 1];
    float a0 = 0.f, a1 = 0.f, a2 = 0.f, a3 = 0.f;
    for (int i = b; i < e; ++i) {
        int g = adj[i];
        uint2 v = *(const uint2*)(ef + (size_t)g * DD + lane * 4);
        a0 += b2f_lo(v.x); a1 += b2f_hi(v.x);
        a2 += b2f_lo(v.y); a3 += b2f_hi(v.y);
    }
    float sc = (e > b) ? 1.f / (float)(e - b) : 0.f;
    float a = *aP;
    float4 bb = ((const float4*)bias)[lane];
    float4 xv = *(const float4*)(x + (size_t)w * DD + lane * 4);
    float4 r;
    r.x = a0 * sc + bb.x + xv.x; r.x = (r.x >= 0.f) ? r.x : a * r.x;
    r.y = a1 * sc + bb.y + xv.y; r.y = (r.y >= 0.f) ? r.y : a * r.y;
    r.z = a2 * sc + bb.z + xv.z; r.z = (r.z >= 0.f) ? r.z : a * r.z;
    r.w = a3 * sc + bb.w + xv.w; r.w = (r.w >= 0.f) ? r.w : a * r.w;
    *(float4*)(out + (size_t)w * DD + lane * 4) = r;
}

extern "C" void kernel_launch(void* const* d_in, const int* in_sizes, int n_in,
                              void* d_out, int out_size, void* d_ws, size_t ws_size,
                              hipStream_t stream) {
    const float* x       = (const float*)d_in[0];
    const float* W1      = (const float*)d_in[1];
    const float* b1      = (const float*)d_in[2];
    const float* W2      = (const float*)d_in[3];
    const float* b2      = (const float*)d_in[4];
    const float* prelu_a = (const float*)d_in[5];
    const int*   hei     = (const int*)d_in[6];
    const int* idx_src = hei;          // hei[0,:] node indices
    const int* idx_he  = hei + NEDGE;  // hei[1,:] hyperedge indices

    float* out = (float*)d_out;
    unsigned short* B1 = (unsigned short*)d_ws;           // [NN*DD] bf16
    unsigned short* B2 = B1 + (size_t)NN * DD;            // [NN*DD] bf16
    int* off_n = (int*)(B2 + (size_t)NN * DD);            // NN+1
    int* off_e = off_n + NN + 1;                          // NHE+1
    int* cur_n = off_e + NHE + 1;                         // NN (counts)
    int* cur_e = cur_n + NN;                              // NHE
    int* adj_n = cur_e + NHE;                             // NEDGE
    int* adj_e = adj_n + NEDGE;                           // NEDGE
    int* bsum  = adj_e + NEDGE;                           // 2*NBLK
    int* bbase = bsum + 2 * NBLK;                         // 2*NBLK + 2
    // d_out doubles as bf16(x) + bf16(W1/W2) until the final kernel
    unsigned short* xb  = (unsigned short*)d_out;         // [NN*DD] bf16
    unsigned short* w1b = xb + (size_t)NN * DD;           // [DD*DD]
    unsigned short* w2b = w1b + DD * DD;                  // [DD*DD]

    const int eblocks = (NEDGE + 255) / 256;
    const int gblocks = (NN * 64 + 255) / 256;
    dim3 ggrid((NN + 127) / 128, DD / 128);

    // ---- CSR build (parallel scan) ----
    hipMemsetAsync(cur_n, 0, sizeof(int) * (NN + NHE), stream);
    k_count<<<eblocks, 256, 0, stream>>>(idx_src, idx_he, cur_n, cur_e);
    k_scan_a<<<2 * NBLK, 256, 0, stream>>>(cur_n, cur_e, bsum);
    k_scan_b<<<1, 64, 0, stream>>>(bsum, bbase);
    k_scan_c<<<2 * NBLK, 256, 0, stream>>>(cur_n, cur_e, bbase, off_n, off_e);
    hipMemsetAsync(cur_n, 0, sizeof(int) * (NN + NHE), stream);
    k_fill<<<eblocks, 256, 0, stream>>>(idx_src, idx_he, off_n, off_e,
                                        cur_n, cur_e, adj_n, adj_e);

    // ---- bf16 conversions ----
    k_cvt<<<(NN * DD / 4 + 255) / 256, 256, 0, stream>>>(x, xb, NN * DD / 4);
    k_cvt<<<(DD * DD / 4 + 255) / 256, 256, 0, stream>>>(W1, w1b, DD * DD / 4);
    k_cvt<<<(DD * DD / 4 + 255) / 256, 256, 0, stream>>>(W2, w2b, DD * DD / 4);

    // ---- layer 1 ----
    k_gemm_bf16<<<ggrid, 256, 0, stream>>>(xb, w1b, B1, NN);              // B1 = bf16(x@W1^T)
    k_gather_edge_b<<<gblocks, 256, 0, stream>>>(B1, B2, off_e, adj_e);   // B2 = ef1
    k_gather_node_mid_b<<<gblocks, 256, 0, stream>>>(B2, B1, off_n, adj_n, b1, prelu_a); // B1 = h1

    // ---- layer 2 ----
    k_gemm_bf16<<<ggrid, 256, 0, stream>>>(B1, w2b, B2, NN);              // B2 = bf16(h1@W2^T)
    k_gather_edge_b<<<gblocks, 256, 0, stream>>>(B2, B1, off_e, adj_e);   // B1 = ef2
    k_gather_node_final_b<<<gblocks, 256, 0, stream>>>(B1, x, out, off_n, adj_n, b2, prelu_a);
}

// Round 5
// 364.716 us; speedup vs baseline: 12.7650x; 1.0908x over previous
//
#include <hip/hip_runtime.h>

#define NN    50000   // nodes
#define NHE   50000   // hyperedges
#define NEDGE 320000  // incidence pairs
#define DD    256     // feature dim

#define SB    1024                    // scan elements per block
#define NBLK  ((NN + SB - 1) / SB)    // 49 blocks per segment (NN == NHE)

typedef float f32x4 __attribute__((ext_vector_type(4)));
typedef short short8 __attribute__((ext_vector_type(8)));

// ---- bf16 helpers (RTNE) ----
static __device__ __forceinline__ unsigned short f2b(float f) {
    union { float f; unsigned u; } c; c.f = f;
    unsigned u = c.u;
    u += 0x7fffu + ((u >> 16) & 1u);
    return (unsigned short)(u >> 16);
}
static __device__ __forceinline__ float b2f_lo(unsigned v) {
    union { unsigned u; float f; } c; c.u = v << 16; return c.f;
}
static __device__ __forceinline__ float b2f_hi(unsigned v) {
    union { unsigned u; float f; } c; c.u = v & 0xffff0000u; return c.f;
}
static __device__ __forceinline__ unsigned pack2(float a, float b) {
    return (unsigned)f2b(a) | ((unsigned)f2b(b) << 16);
}

// ---------------- CSR build ----------------
__global__ __launch_bounds__(256) void k_count(const int* __restrict__ src,
                                               const int* __restrict__ he,
                                               int* __restrict__ cnt_n,
                                               int* __restrict__ cnt_e) {
    int e = blockIdx.x * 256 + threadIdx.x;
    if (e >= NEDGE) return;
    atomicAdd(&cnt_n[src[e]], 1);
    atomicAdd(&cnt_e[he[e]], 1);
}

__global__ __launch_bounds__(256) void k_scan_a(const int* __restrict__ cnt_n,
                                                const int* __restrict__ cnt_e,
                                                int* __restrict__ bsum) {
    int b   = blockIdx.x;            // 0 .. 2*NBLK-1
    int seg = b / NBLK, lb = b % NBLK;
    const int* cnt = seg ? cnt_e : cnt_n;
    int t = threadIdx.x;
    int idx = lb * SB + t * 4;
    int s = 0;
#pragma unroll
    for (int j = 0; j < 4; ++j)
        if (idx + j < NN) s += cnt[idx + j];
    __shared__ int red[256];
    red[t] = s;
    __syncthreads();
    for (int o = 128; o > 0; o >>= 1) {
        if (t < o) red[t] += red[t + o];
        __syncthreads();
    }
    if (t == 0) bsum[b] = red[0];
}

__global__ __launch_bounds__(64) void k_scan_b(const int* __restrict__ bsum,
                                               int* __restrict__ bbase) {
    if (threadIdx.x == 0) {
        int r = 0;
        for (int i = 0; i < NBLK; ++i) { bbase[i] = r; r += bsum[i]; }
        bbase[2 * NBLK] = r;
        r = 0;
        for (int i = NBLK; i < 2 * NBLK; ++i) { bbase[i] = r; r += bsum[i]; }
        bbase[2 * NBLK + 1] = r;
    }
}

__global__ __launch_bounds__(256) void k_scan_c(const int* __restrict__ cnt_n,
                                                const int* __restrict__ cnt_e,
                                                const int* __restrict__ bbase,
                                                int* __restrict__ off_n,
                                                int* __restrict__ off_e) {
    int b   = blockIdx.x;
    int seg = b / NBLK, lb = b % NBLK;
    const int* cnt = seg ? cnt_e : cnt_n;
    int* off = seg ? off_e : off_n;
    int t = threadIdx.x;
    int idx = lb * SB + t * 4;
    int v[4];
    int tsum = 0;
#pragma unroll
    for (int j = 0; j < 4; ++j) {
        v[j] = (idx + j < NN) ? cnt[idx + j] : 0;
        tsum += v[j];
    }
    __shared__ int sc[256];
    sc[t] = tsum;
    __syncthreads();
    for (int o = 1; o < 256; o <<= 1) {
        int val = (t >= o) ? sc[t - o] : 0;
        __syncthreads();
        sc[t] += val;
        __syncthreads();
    }
    int p = bbase[b] + sc[t] - tsum;
#pragma unroll
    for (int j = 0; j < 4; ++j) {
        if (idx + j < NN) off[idx + j] = p;
        p += v[j];
    }
    if (b == 0 && t == 0) off_n[NN] = bbase[2 * NBLK];
    if (b == NBLK && t == 0) off_e[NHE] = bbase[2 * NBLK + 1];
}

__global__ __launch_bounds__(256) void k_fill(const int* __restrict__ src,
                                              const int* __restrict__ he,
                                              const int* __restrict__ off_n,
                                              const int* __restrict__ off_e,
                                              int* __restrict__ cur_n,
                                              int* __restrict__ cur_e,
                                              int* __restrict__ adj_n,
                                              int* __restrict__ adj_e) {
    int e = blockIdx.x * 256 + threadIdx.x;
    if (e >= NEDGE) return;
    int s = src[e], h = he[e];
    int pn = off_n[s] + atomicAdd(&cur_n[s], 1);
    adj_n[pn] = h;
    int pe = off_e[h] + atomicAdd(&cur_e[h], 1);
    adj_e[pe] = s;
}

// ---------------- weights fp32 -> bf16 (both W in one launch) ----------------
__global__ __launch_bounds__(256) void k_cvt_w(const float* __restrict__ w1,
                                               const float* __restrict__ w2,
                                               unsigned short* __restrict__ o1,
                                               unsigned short* __restrict__ o2) {
    int t = blockIdx.x * 256 + threadIdx.x;          // 0 .. 2*DD*DD/4-1
    const int n4 = DD * DD / 4;
    const float* s = (t < n4) ? w1 : w2;
    unsigned short* d = (t < n4) ? o1 : o2;
    int i = (t < n4) ? t : t - n4;
    float4 v = ((const float4*)s)[i];
    uint2 o;
    o.x = pack2(v.x, v.y);
    o.y = pack2(v.z, v.w);
    ((uint2*)d)[i] = o;
}

// ---------------- bf16 MFMA GEMM: C[m,n] = sum_k A[m,k]*W[n,k] ----------------
// A32: A is fp32 (converted to bf16 during LDS staging); else A is bf16.
template <bool A32>
__global__ __launch_bounds__(256) void k_gemm_bf16(const void* __restrict__ Av,
                                                   const unsigned short* __restrict__ Wb,
                                                   unsigned short* __restrict__ Cb, int M) {
    __shared__ __align__(16) unsigned short As[128 * 32];
    __shared__ __align__(16) unsigned short Bs[128 * 32];
    const int t    = threadIdx.x;
    const int m0   = blockIdx.x * 128;
    const int n0   = blockIdx.y * 128;
    const int lane = t & 63;
    const int wave = t >> 6;
    const int wm   = (wave >> 1) * 64;
    const int wn   = (wave & 1) * 64;
    const int fr   = lane & 15;
    const int fq   = lane >> 4;

    f32x4 acc[4][4] = {};

    const int sr = t >> 2;
    const int ss = t & 3;

    for (int k0 = 0; k0 < DD; k0 += 32) {
        __syncthreads();
#pragma unroll
        for (int i = 0; i < 2; ++i) {
            int r  = sr + i * 64;
            int gm = m0 + r;
            uint4 av = make_uint4(0u, 0u, 0u, 0u);
            if (gm < M) {
                if (A32) {
                    const float* p = (const float*)Av + (size_t)gm * DD + k0 + ss * 8;
                    float4 f0 = *(const float4*)p;
                    float4 f1 = *(const float4*)(p + 4);
                    av.x = pack2(f0.x, f0.y);
                    av.y = pack2(f0.z, f0.w);
                    av.z = pack2(f1.x, f1.y);
                    av.w = pack2(f1.z, f1.w);
                } else {
                    av = *(const uint4*)((const unsigned short*)Av + (size_t)gm * DD + k0 + ss * 8);
                }
            }
            *(uint4*)(As + r * 32 + ((ss ^ (r & 3)) * 8)) = av;
            uint4 bv = *(const uint4*)(Wb + (size_t)(n0 + r) * DD + k0 + ss * 8);
            *(uint4*)(Bs + r * 32 + ((ss ^ (r & 3)) * 8)) = bv;
        }
        __syncthreads();

        short8 af[4], bf[4];
#pragma unroll
        for (int mt = 0; mt < 4; ++mt) {
            int r = wm + mt * 16 + fr;
            af[mt] = *(const short8*)(As + r * 32 + ((fq ^ (r & 3)) * 8));
        }
#pragma unroll
        for (int nt = 0; nt < 4; ++nt) {
            int r = wn + nt * 16 + fr;
            bf[nt] = *(const short8*)(Bs + r * 32 + ((fq ^ (r & 3)) * 8));
        }
#pragma unroll
        for (int mt = 0; mt < 4; ++mt)
#pragma unroll
            for (int nt = 0; nt < 4; ++nt)
                acc[mt][nt] = __builtin_amdgcn_mfma_f32_16x16x32_bf16(af[mt], bf[nt],
                                                                      acc[mt][nt], 0, 0, 0);
    }

    // C/D layout: col = lane&15, row = quad*4 + reg
#pragma unroll
    for (int mt = 0; mt < 4; ++mt) {
#pragma unroll
        for (int i = 0; i < 4; ++i) {
            int gm = m0 + wm + mt * 16 + fq * 4 + i;
            if (gm >= M) continue;
#pragma unroll
            for (int nt = 0; nt < 4; ++nt) {
                int gn = n0 + wn + nt * 16 + fr;
                Cb[(size_t)gm * DD + gn] = f2b(acc[mt][nt][i]);
            }
        }
    }
}

// ---------------- gather core: unroll-4 neighbor batches, 4 loads in flight ----
// Validity branches are wave-uniform (b,e uniform per wave) -> no divergence.
// Clamped duplicate indices re-load a just-fetched line (L1 hit, ~free).
static __device__ __forceinline__ void gather4(const unsigned short* __restrict__ srcb,
                                               const int* __restrict__ adj,
                                               int b, int e, int lane,
                                               float& a0, float& a1, float& a2, float& a3) {
    a0 = a1 = a2 = a3 = 0.f;
    for (int i = b; i < e; i += 4) {
        int g0 = adj[i];
        int g1 = (i + 1 < e) ? adj[i + 1] : g0;
        int g2 = (i + 2 < e) ? adj[i + 2] : g0;
        int g3 = (i + 3 < e) ? adj[i + 3] : g0;
        uint2 v0 = *(const uint2*)(srcb + (size_t)g0 * DD + lane * 4);
        uint2 v1 = *(const uint2*)(srcb + (size_t)g1 * DD + lane * 4);
        uint2 v2 = *(const uint2*)(srcb + (size_t)g2 * DD + lane * 4);
        uint2 v3 = *(const uint2*)(srcb + (size_t)g3 * DD + lane * 4);
        a0 += b2f_lo(v0.x); a1 += b2f_hi(v0.x); a2 += b2f_lo(v0.y); a3 += b2f_hi(v0.y);
        if (i + 1 < e) { a0 += b2f_lo(v1.x); a1 += b2f_hi(v1.x); a2 += b2f_lo(v1.y); a3 += b2f_hi(v1.y); }
        if (i + 2 < e) { a0 += b2f_lo(v2.x); a1 += b2f_hi(v2.x); a2 += b2f_lo(v2.y); a3 += b2f_hi(v2.y); }
        if (i + 3 < e) { a0 += b2f_lo(v3.x); a1 += b2f_hi(v3.x); a2 += b2f_lo(v3.y); a3 += b2f_hi(v3.y); }
    }
}

__global__ __launch_bounds__(256) void k_gather_edge_b(const unsigned short* __restrict__ xw,
                                                       unsigned short* __restrict__ ef,
                                                       const int* __restrict__ off,
                                                       const int* __restrict__ adj) {
    int w = (blockIdx.x * 256 + threadIdx.x) >> 6;
    int lane = threadIdx.x & 63;
    if (w >= NHE) return;
    int b = off[w], e = off[w + 1];
    float a0, a1, a2, a3;
    gather4(xw, adj, b, e, lane, a0, a1, a2, a3);
    float sc = (e > b) ? 1.f / (float)(e - b) : 0.f;
    uint2 o;
    o.x = pack2(a0 * sc, a1 * sc);
    o.y = pack2(a2 * sc, a3 * sc);
    *(uint2*)(ef + (size_t)w * DD + lane * 4) = o;
}

__global__ __launch_bounds__(256) void k_gather_node_mid_b(const unsigned short* __restrict__ ef,
                                                           unsigned short* __restrict__ h,
                                                           const int* __restrict__ off,
                                                           const int* __restrict__ adj,
                                                           const float* __restrict__ bias,
                                                           const float* __restrict__ aP) {
    int w = (blockIdx.x * 256 + threadIdx.x) >> 6;
    int lane = threadIdx.x & 63;
    if (w >= NN) return;
    int b = off[w], e = off[w + 1];
    float a0, a1, a2, a3;
    gather4(ef, adj, b, e, lane, a0, a1, a2, a3);
    float sc = (e > b) ? 1.f / (float)(e - b) : 0.f;
    float a = *aP;
    float4 bb = ((const float4*)bias)[lane];
    float r0 = a0 * sc + bb.x; r0 = (r0 >= 0.f) ? r0 : a * r0;
    float r1 = a1 * sc + bb.y; r1 = (r1 >= 0.f) ? r1 : a * r1;
    float r2 = a2 * sc + bb.z; r2 = (r2 >= 0.f) ? r2 : a * r2;
    float r3 = a3 * sc + bb.w; r3 = (r3 >= 0.f) ? r3 : a * r3;
    uint2 o;
    o.x = pack2(r0, r1);
    o.y = pack2(r2, r3);
    *(uint2*)(h + (size_t)w * DD + lane * 4) = o;
}

__global__ __launch_bounds__(256) void k_gather_node_final_b(const unsigned short* __restrict__ ef,
                                                             const float* __restrict__ x,
                                                             float* __restrict__ out,
                                                             const int* __restrict__ off,
                                                             const int* __restrict__ adj,
                                                             const float* __restrict__ bias,
                                                             const float* __restrict__ aP) {
    int w = (blockIdx.x * 256 + threadIdx.x) >> 6;
    int lane = threadIdx.x & 63;
    if (w >= NN) return;
    int b = off[w], e = off[w + 1];
    float a0, a1, a2, a3;
    gather4(ef, adj, b, e, lane, a0, a1, a2, a3);
    float sc = (e > b) ? 1.f / (float)(e - b) : 0.f;
    float a = *aP;
    float4 bb = ((const float4*)bias)[lane];
    float4 xv = *(const float4*)(x + (size_t)w * DD + lane * 4);
    float4 r;
    r.x = a0 * sc + bb.x + xv.x; r.x = (r.x >= 0.f) ? r.x : a * r.x;
    r.y = a1 * sc + bb.y + xv.y; r.y = (r.y >= 0.f) ? r.y : a * r.y;
    r.z = a2 * sc + bb.z + xv.z; r.z = (r.z >= 0.f) ? r.z : a * r.z;
    r.w = a3 * sc + bb.w + xv.w; r.w = (r.w >= 0.f) ? r.w : a * r.w;
    *(float4*)(out + (size_t)w * DD + lane * 4) = r;
}

extern "C" void kernel_launch(void* const* d_in, const int* in_sizes, int n_in,
                              void* d_out, int out_size, void* d_ws, size_t ws_size,
                              hipStream_t stream) {
    const float* x       = (const float*)d_in[0];
    const float* W1      = (const float*)d_in[1];
    const float* b1      = (const float*)d_in[2];
    const float* W2      = (const float*)d_in[3];
    const float* b2      = (const float*)d_in[4];
    const float* prelu_a = (const float*)d_in[5];
    const int*   hei     = (const int*)d_in[6];
    const int* idx_src = hei;          // hei[0,:] node indices
    const int* idx_he  = hei + NEDGE;  // hei[1,:] hyperedge indices

    float* out = (float*)d_out;
    unsigned short* B1 = (unsigned short*)d_ws;           // [NN*DD] bf16
    unsigned short* B2 = B1 + (size_t)NN * DD;            // [NN*DD] bf16
    int* off_n = (int*)(B2 + (size_t)NN * DD);            // NN+1
    int* off_e = off_n + NN + 1;                          // NHE+1
    int* cur_n = off_e + NHE + 1;                         // NN (counts)
    int* cur_e = cur_n + NN;                              // NHE
    int* adj_n = cur_e + NHE;                             // NEDGE
    int* adj_e = adj_n + NEDGE;                           // NEDGE
    int* bsum  = adj_e + NEDGE;                           // 2*NBLK
    int* bbase = bsum + 2 * NBLK;                         // 2*NBLK + 2
    // d_out doubles as bf16 weight storage until the final kernel
    unsigned short* w1b = (unsigned short*)d_out;         // [DD*DD]
    unsigned short* w2b = w1b + DD * DD;                  // [DD*DD]

    const int eblocks = (NEDGE + 255) / 256;
    const int gblocks = (NN * 64 + 255) / 256;
    dim3 ggrid((NN + 127) / 128, DD / 128);

    // ---- CSR build (parallel scan) ----
    hipMemsetAsync(cur_n, 0, sizeof(int) * (NN + NHE), stream);
    k_count<<<eblocks, 256, 0, stream>>>(idx_src, idx_he, cur_n, cur_e);
    k_scan_a<<<2 * NBLK, 256, 0, stream>>>(cur_n, cur_e, bsum);
    k_scan_b<<<1, 64, 0, stream>>>(bsum, bbase);
    k_scan_c<<<2 * NBLK, 256, 0, stream>>>(cur_n, cur_e, bbase, off_n, off_e);
    hipMemsetAsync(cur_n, 0, sizeof(int) * (NN + NHE), stream);
    k_fill<<<eblocks, 256, 0, stream>>>(idx_src, idx_he, off_n, off_e,
                                        cur_n, cur_e, adj_n, adj_e);

    // ---- weight conversions (x conversion fused into GEMM1) ----
    k_cvt_w<<<(2 * DD * DD / 4 + 255) / 256, 256, 0, stream>>>(W1, W2, w1b, w2b);

    // ---- layer 1 ----
    k_gemm_bf16<true><<<ggrid, 256, 0, stream>>>((const void*)x, w1b, B1, NN);   // B1 = bf16(x@W1^T)
    k_gather_edge_b<<<gblocks, 256, 0, stream>>>(B1, B2, off_e, adj_e);          // B2 = ef1
    k_gather_node_mid_b<<<gblocks, 256, 0, stream>>>(B2, B1, off_n, adj_n, b1, prelu_a); // B1 = h1

    // ---- layer 2 ----
    k_gemm_bf16<false><<<ggrid, 256, 0, stream>>>((const void*)B1, w2b, B2, NN); // B2 = bf16(h1@W2^T)
    k_gather_edge_b<<<gblocks, 256, 0, stream>>>(B2, B1, off_e, adj_e);          // B1 = ef2
    k_gather_node_final_b<<<gblocks, 256, 0, stream>>>(B1, x, out, off_n, adj_n, b2, prelu_a);
}